// Round 12
// baseline (822.393 us; speedup 1.0000x reference)
//
#include <hip/hip_runtime.h>
#include <math.h>

#define NN 50000
#define NE 800000
#define IND 256
#define HD 128
#define NH 4
#define NC 32
#define RELN 100
#define RD 16
#define EHD 32

typedef unsigned int uint;
typedef _Float16 half2_t __attribute__((ext_vector_type(2)));

__device__ inline uint pack_bf16(float a, float b) {
    uint ua = __float_as_uint(a), ub = __float_as_uint(b);
    ua += 0x7fffu + ((ua >> 16) & 1u);
    ub += 0x7fffu + ((ub >> 16) & 1u);
    return (ua >> 16) | (ub & 0xffff0000u);
}

__device__ inline uint pack_f16(float a, float b) {
    half2_t h = { (_Float16)a, (_Float16)b };
    return __builtin_bit_cast(uint, h);
}

#if __has_builtin(__builtin_amdgcn_fdot2)
#define FDOT2(a, b, c) __builtin_amdgcn_fdot2((a), (b), (c), false)
#else
static __device__ inline float FDOT2(half2_t a, half2_t b, float c) {
    return c + (float)a.x * (float)b.x + (float)a.y * (float)b.y;
}
#endif

// 16-lane (head-group) sum via DPP row ops
__device__ inline float dpp_add(float a, const int ctrl) {
    int t;
    switch (ctrl) {
        case 0: t = __builtin_amdgcn_update_dpp(0, __float_as_int(a), 0xB1,  0xF, 0xF, true); break;
        case 1: t = __builtin_amdgcn_update_dpp(0, __float_as_int(a), 0x4E,  0xF, 0xF, true); break;
        case 2: t = __builtin_amdgcn_update_dpp(0, __float_as_int(a), 0x141, 0xF, 0xF, true); break;
        default:t = __builtin_amdgcn_update_dpp(0, __float_as_int(a), 0x140, 0xF, 0xF, true); break;
    }
    return a + __int_as_float(t);
}
__device__ inline float dpp_reduce16(float a) {
    a = dpp_add(a, 0);
    a = dpp_add(a, 1);
    a = dpp_add(a, 2);
    a = dpp_add(a, 3);
    return a;
}

// ---------------- degree count ----------------
__global__ __launch_bounds__(256) void count_kernel(
    const int* __restrict__ dst, int* __restrict__ counts)
{
    int e = blockIdx.x * 256 + threadIdx.x;
    if (e < NE) atomicAdd(&counts[dst[e]], 1);
}

// ---------------- hierarchical scan: A (per-block), B (partials), C (add) ----
__global__ __launch_bounds__(1024) void scan_a_kernel(
    const int* __restrict__ counts, int* __restrict__ row_ptr,
    int* __restrict__ partials, int n)
{
    __shared__ int wsum[16];
    int tid = threadIdx.x;
    int i = blockIdx.x * 1024 + tid;
    int v = (i < n) ? counts[i] : 0;
    int lane = tid & 63;
    int incl = v;
#pragma unroll
    for (int off = 1; off < 64; off <<= 1) {
        int t = __shfl_up(incl, off);
        if (lane >= off) incl += t;
    }
    if (lane == 63) wsum[tid >> 6] = incl;
    __syncthreads();
    if (tid < 16) {
        int w = wsum[tid];
        int inc2 = w;
#pragma unroll
        for (int off = 1; off < 16; off <<= 1) {
            int u = __shfl_up(inc2, off);
            if (tid >= off) inc2 += u;
        }
        wsum[tid] = inc2 - w;
    }
    __syncthreads();
    int excl = wsum[tid >> 6] + incl - v;
    if (i < n) row_ptr[i] = excl;
    if (tid == 1023) partials[blockIdx.x] = excl + v;
}

__global__ __launch_bounds__(64) void scan_b_kernel(
    int* __restrict__ partials, int* __restrict__ row_ptr, int nblk, int n)
{
    int tid = threadIdx.x;
    int v = (tid < nblk) ? partials[tid] : 0;
    int incl = v;
#pragma unroll
    for (int off = 1; off < 64; off <<= 1) {
        int t = __shfl_up(incl, off);
        if (tid >= off) incl += t;
    }
    if (tid < nblk) partials[tid] = incl - v;
    if (tid == nblk - 1) row_ptr[n] = incl;
}

__global__ __launch_bounds__(1024) void scan_c_kernel(
    int* __restrict__ row_ptr, int* __restrict__ cursor,
    const int* __restrict__ partials, int n)
{
    int i = blockIdx.x * 1024 + threadIdx.x;
    if (i < n) {
        int r = row_ptr[i] + partials[blockIdx.x];
        row_ptr[i] = r;
        cursor[i] = r;
    }
}

// ------- edge feature MLPs + CSR placement (fused fill), edge order -------
__global__ __launch_bounds__(256) void edge_feat_fill_kernel(
    const float* __restrict__ eattr, const int* __restrict__ src,
    const int* __restrict__ dst, int* __restrict__ cursor,
    const float* __restrict__ dW1, const float* __restrict__ db1,
    const float* __restrict__ dW2, const float* __restrict__ db2,
    const float* __restrict__ cW1, const float* __restrict__ cb1,
    const float* __restrict__ cW2, const float* __restrict__ cb2,
    const float* __restrict__ rel_emb,
    const float* __restrict__ fW1, const float* __restrict__ fb1,
    const float* __restrict__ fg,  const float* __restrict__ fbl,
    const float* __restrict__ fW2, const float* __restrict__ fb2,
    uint4* __restrict__ efeat_h, int2* __restrict__ meta_c)
{
    int e = blockIdx.x * 256 + threadIdx.x;
    // init the pad region (positions NE..NE+7) so un-clamped batch reads are safe
    if (e < 8) {
        meta_c[NE + e] = make_int2(0, 0);
        uint4 z = {0u, 0u, 0u, 0u};
        efeat_h[(size_t)(NE + e) * 2 + 0] = z;
        efeat_h[(size_t)(NE + e) * 2 + 1] = z;
    }
    if (e >= NE) return;
    float d  = eattr[(size_t)e * 3 + 0];
    float cx = eattr[(size_t)e * 3 + 1];
    int r = (int)eattr[(size_t)e * 3 + 2];
    r = min(max(r, 0), RELN - 1);
    int p = atomicAdd(&cursor[dst[e]], 1);     // CSR slot
    meta_c[p] = make_int2(src[e], __float_as_int(__log2f(d)));

    float df[RD], cf[RD];
#pragma unroll
    for (int k = 0; k < RD; k++) { df[k] = db2[k]; cf[k] = cb2[k]; }
    for (int j = 0; j < EHD; j++) {
        float h1 = fmaxf(d  * dW1[j] + db1[j], 0.f);
        float h2 = fmaxf(cx * cW1[j] + cb1[j], 0.f);
#pragma unroll
        for (int k = 0; k < RD; k++) {
            df[k] += h1 * dW2[j * RD + k];
            cf[k] += h2 * cW2[j * RD + k];
        }
    }
    float hh[2 * RD];
#pragma unroll
    for (int m = 0; m < 2 * RD; m++) hh[m] = fb1[m];
    for (int k = 0; k < RD; k++) {
        float a = df[k], b = cf[k], c = rel_emb[r * RD + k];
#pragma unroll
        for (int m = 0; m < 2 * RD; m++) {
            hh[m] += a * fW1[k * (2 * RD) + m]
                   + b * fW1[(RD + k) * (2 * RD) + m]
                   + c * fW1[(2 * RD + k) * (2 * RD) + m];
        }
    }
    float s = 0.f;
#pragma unroll
    for (int m = 0; m < 2 * RD; m++) s += hh[m];
    float mean = s * (1.f / (2 * RD));
    float s2 = 0.f;
#pragma unroll
    for (int m = 0; m < 2 * RD; m++) { float dd = hh[m] - mean; s2 += dd * dd; }
    float rs = rsqrtf(s2 * (1.f / (2 * RD)) + 1e-5f);
#pragma unroll
    for (int m = 0; m < 2 * RD; m++)
        hh[m] = fmaxf((hh[m] - mean) * rs * fg[m] + fbl[m], 0.f);

    float ef[RD];
#pragma unroll
    for (int k = 0; k < RD; k++) ef[k] = fb2[k];
    for (int m = 0; m < 2 * RD; m++) {
        float hv = hh[m];
#pragma unroll
        for (int k = 0; k < RD; k++) ef[k] += hv * fW2[m * RD + k];
    }
    uint4 e0, e1;
    e0.x = pack_f16(ef[0],  ef[1]);  e0.y = pack_f16(ef[2],  ef[3]);
    e0.z = pack_f16(ef[4],  ef[5]);  e0.w = pack_f16(ef[6],  ef[7]);
    e1.x = pack_f16(ef[8],  ef[9]);  e1.y = pack_f16(ef[10], ef[11]);
    e1.z = pack_f16(ef[12], ef[13]); e1.w = pack_f16(ef[14], ef[15]);
    efeat_h[(size_t)p * 2 + 0] = e0;
    efeat_h[(size_t)p * 2 + 1] = e1;
}

// ---------------- input LN + projection (8 nodes / block) ----------------
__global__ __launch_bounds__(256) void ln_proj_kernel(
    const float* __restrict__ x, const float* __restrict__ g, const float* __restrict__ b,
    const float* __restrict__ W, const float* __restrict__ pb, float* __restrict__ x0)
{
    __shared__ float xr[8][IND];
    __shared__ float mv[8][2];
    int nb = blockIdx.x * 8;
    int tid = threadIdx.x;
    const float4* xv = (const float4*)(x + (size_t)nb * IND);
    float4* xl = (float4*)&xr[0][0];
    xl[tid] = xv[tid];
    xl[tid + 256] = xv[tid + 256];
    __syncthreads();
    int node = tid >> 5, lane = tid & 31;
    float s1 = 0.f, s2 = 0.f;
#pragma unroll
    for (int j = 0; j < 8; j++) { float v = xr[node][lane + 32 * j]; s1 += v; s2 += v * v; }
#pragma unroll
    for (int off = 16; off >= 1; off >>= 1) { s1 += __shfl_xor(s1, off); s2 += __shfl_xor(s2, off); }
    if (lane == 0) {
        float mean = s1 * (1.f / IND);
        mv[node][0] = mean;
        mv[node][1] = rsqrtf(s2 * (1.f / IND) - mean * mean + 1e-5f);
    }
    __syncthreads();
#pragma unroll
    for (int j = 0; j < 8; j++) {
        int k = lane + 32 * j;
        xr[node][k] = (xr[node][k] - mv[node][0]) * mv[node][1] * g[k] + b[k];
    }
    __syncthreads();
    int col = tid & 127, r0 = (tid >> 7) * 4;
    float acc[4] = {0.f, 0.f, 0.f, 0.f};
    for (int k = 0; k < IND; k += 4) {
        float4 x4[4];
#pragma unroll
        for (int r = 0; r < 4; r++) x4[r] = *(const float4*)&xr[r0 + r][k];
        float w0 = W[(k + 0) * HD + col];
        float w1 = W[(k + 1) * HD + col];
        float w2 = W[(k + 2) * HD + col];
        float w3 = W[(k + 3) * HD + col];
#pragma unroll
        for (int r = 0; r < 4; r++)
            acc[r] += x4[r].x * w0 + x4[r].y * w1 + x4[r].z * w2 + x4[r].w * w3;
    }
    float pbv = pb[col];
#pragma unroll
    for (int r = 0; r < 4; r++)
        x0[(size_t)(nb + r0 + r) * HD + col] = acc[r] + pbv;
}

// ------- xs = bf16-packed x@Wsrc ; xd = f32 x@Wdst -------
__global__ __launch_bounds__(512) void gemm_sd_kernel(
    const float* __restrict__ x, const float* __restrict__ Ws, const float* __restrict__ Wd,
    uint* __restrict__ xs_p, float2* __restrict__ xd2)
{
    __shared__ float xt[32][HD];
    int nb = blockIdx.x * 32;
    int tid = threadIdx.x;
    const float4* xv = (const float4*)(x + (size_t)nb * HD);
    float4* xl = (float4*)&xt[0][0];
    int validf4 = (NN - nb >= 32) ? 1024 : (NN - nb) * 32;
#pragma unroll
    for (int u = 0; u < 2; u++) {
        int idx = tid + u * 512;
        float4 v = {0.f, 0.f, 0.f, 0.f};
        if (idx < validf4) v = xv[idx];
        xl[idx] = v;
    }
    __syncthreads();
    int half = tid >> 8;                 // 0: xs(bf16)   1: xd(f32)
    int t = tid & 255;
    int q = t & 31;                      // col quad: cols 4q..4q+3
    int r0 = (t >> 5) * 4;               // 4 rows
    const float4* W4 = (const float4*)(half ? Wd : Ws);
    float4 acc[4] = { {0,0,0,0}, {0,0,0,0}, {0,0,0,0}, {0,0,0,0} };
    for (int k = 0; k < HD; k += 4) {
        float4 xr[4];
#pragma unroll
        for (int r = 0; r < 4; r++) xr[r] = *(const float4*)&xt[r0 + r][k];
        float4 w0 = W4[(k + 0) * 32 + q];
        float4 w1 = W4[(k + 1) * 32 + q];
        float4 w2 = W4[(k + 2) * 32 + q];
        float4 w3 = W4[(k + 3) * 32 + q];
#pragma unroll
        for (int r = 0; r < 4; r++) {
            acc[r].x += xr[r].x * w0.x + xr[r].y * w1.x + xr[r].z * w2.x + xr[r].w * w3.x;
            acc[r].y += xr[r].x * w0.y + xr[r].y * w1.y + xr[r].z * w2.y + xr[r].w * w3.y;
            acc[r].z += xr[r].x * w0.z + xr[r].y * w1.z + xr[r].z * w2.z + xr[r].w * w3.z;
            acc[r].w += xr[r].x * w0.w + xr[r].y * w1.w + xr[r].z * w2.w + xr[r].w * w3.w;
        }
    }
    if (half == 0) {
#pragma unroll
        for (int r = 0; r < 4; r++) {
            int n = nb + r0 + r;
            if (n < NN) {
                uint2 pk;
                pk.x = pack_bf16(acc[r].x, acc[r].y);
                pk.y = pack_bf16(acc[r].z, acc[r].w);
                *(uint2*)&xs_p[(size_t)n * 64 + 2 * q] = pk;
            }
        }
    } else {
#pragma unroll
        for (int r = 0; r < 4; r++) {
            int n = nb + r0 + r;
            if (n < NN) {
                float2* o = &xd2[(size_t)n * 64 + 2 * q];
                o[0] = make_float2(acc[r].x, acc[r].y);
                o[1] = make_float2(acc[r].z, acc[r].w);
            }
        }
    }
}

// ------- per-layer attention aggregate + LN + ELU + residual -------
// wave = worker over an EDGE-BALANCED contiguous node range (binary search);
// forced pipeline (sched_barrier), DPP reduce, padded no-clamp loads.
// NOTE: distance weight multiplies the LOGIT (a *= dw^sc) BEFORE exp — R11's
// exp-side fusion was wrong math.
__global__ __launch_bounds__(256) void aggregate_kernel(
    const uint* __restrict__ xs_p, const float2* __restrict__ xd2,
    const uint4* __restrict__ efeat_h, const int2* __restrict__ meta_c,
    const int* __restrict__ row_ptr,
    const float* __restrict__ Wedge_i, const float2* __restrict__ att2,
    const float* __restrict__ sscale_i, const float2* __restrict__ ng2,
    const float2* __restrict__ nb2, float2* __restrict__ xio2,
    int apply_dist, int nwaves)
{
    int l = threadIdx.x & 63;
    int wid = blockIdx.x * 4 + __builtin_amdgcn_readfirstlane(threadIdx.x >> 6);

    // -------- layer constants: loaded ONCE per wave --------
    int c0 = 2 * l, c1 = 2 * l + 1;
    half2_t wxh[8], wyh[8];
#pragma unroll
    for (int q = 0; q < 8; q++) {
        wxh[q] = (half2_t){ (_Float16)Wedge_i[(2 * q) * HD + c0],
                            (_Float16)Wedge_i[(2 * q + 1) * HD + c0] };
        wyh[q] = (half2_t){ (_Float16)Wedge_i[(2 * q) * HD + c1],
                            (_Float16)Wedge_i[(2 * q + 1) * HD + c1] };
    }
    float2 attv = att2[l];
    float sc = sscale_i[l >> 4];
    float2 g = ng2[l], bb = nb2[l];

    // -------- edge-balanced node range [nlo, nhi) --------
    int t0 = (int)((long long)wid * NE / nwaves);
    int t1 = (int)((long long)(wid + 1) * NE / nwaves);
    int lo = 0, hi = NN;
    while (lo < hi) { int mid = (lo + hi) >> 1; if (row_ptr[mid] < t0) lo = mid + 1; else hi = mid; }
    int nlo = lo;
    hi = NN;
    while (lo < hi) { int mid = (lo + hi) >> 1; if (row_ptr[mid] < t1) lo = mid + 1; else hi = mid; }
    int nhi = (wid == nwaves - 1) ? NN : lo;
    if (nlo >= nhi) return;

    auto loadB = [&](int b, int2* mt, uint* xw, uint4 (*ef)[2]) {
#pragma unroll
        for (int j = 0; j < 4; j++) {
            mt[j] = meta_c[b + j];
            ef[j][0] = efeat_h[(size_t)(b + j) * 2 + 0];
            ef[j][1] = efeat_h[(size_t)(b + j) * 2 + 1];
        }
#pragma unroll
        for (int j = 0; j < 4; j++) xw[j] = xs_p[(size_t)mt[j].x * 64 + l];
    };

    auto computeB = [&](int b, int e1, const int2* mt, const uint* xw,
                        const uint4 (*ef)[2], float2 xdv,
                        float& esum, float2& macc) {
#pragma unroll
        for (int j = 0; j < 4; j++) {
            const half2_t* eh = (const half2_t*)&ef[j][0];
            float efx = 0.f, efy = 0.f;
#pragma unroll
            for (int q = 0; q < 8; q++) {
                efx = FDOT2(eh[q], wxh[q], efx);
                efy = FDOT2(eh[q], wyh[q], efy);
            }
            float xvx = __uint_as_float(xw[j] << 16);
            float xvy = __uint_as_float(xw[j] & 0xffff0000u);
            float zx = xvx + xdv.x + efx;
            float zy = xvy + xdv.y + efy;
            // tanh: 1 - 2/(exp2(z*2log2e)+1)
            float px = exp2f(zx * 2.88539008f);
            float py = exp2f(zy * 2.88539008f);
            float tx = __builtin_fmaf(-2.f, __builtin_amdgcn_rcpf(px + 1.f), 1.f);
            float ty = __builtin_fmaf(-2.f, __builtin_amdgcn_rcpf(py + 1.f), 1.f);
            float a = tx * attv.x + ty * attv.y;
            a = dpp_reduce16(a);                 // 16-lane head-group sum
            // distance weight scales the LOGIT: a *= dw^sc = exp2(lg2(dw)*sc)
            if (apply_dist) a *= exp2f(__int_as_float(mt[j].y) * sc);
            float ea = exp2f(a * 1.44269504f);   // exp(a)
            ea = (b + j < e1) ? ea : 0.f;
            esum += ea;
            macc.x += xvx * ea;
            macc.y += xvy * ea;
        }
    };

    auto epilogue = [&](int node, float esum, float2 macc, float2 xres) {
        float inv = __builtin_amdgcn_rcpf(esum + 1e-8f);
        float2 outv = { macc.x * inv, macc.y * inv };
        float s1 = outv.x + outv.y;
        float s2 = outv.x * outv.x + outv.y * outv.y;
#pragma unroll
        for (int off = 32; off >= 1; off >>= 1) { s1 += __shfl_xor(s1, off); s2 += __shfl_xor(s2, off); }
        float mean = s1 * (1.f / HD);
        float var = s2 * (1.f / HD) - mean * mean;
        float rstd = rsqrtf(var + 1e-5f);
        float yx = (outv.x - mean) * rstd * g.x + bb.x;
        float yy = (outv.y - mean) * rstd * g.y + bb.y;
        float ex = (yx > 0.f) ? yx : expm1f(yx);
        float ey = (yy > 0.f) ? yy : expm1f(yy);
        float2 res;
        res.x = ex + xres.x;
        res.y = ey + xres.y;
        xio2[(size_t)node * 64 + l] = res;
    };

    int node = nlo;
    int e0 = row_ptr[node], e1 = row_ptr[node + 1];
    float2 xdv  = xd2[(size_t)node * 64 + l];
    float2 xres = xio2[(size_t)node * 64 + l];
    int2 mt[4], mtn[4];
    uint xw[4], xwn[4];
    uint4 ef[4][2], efn[4][2];
    if (e0 < e1) loadB(e0, mt, xw, ef);
    float esum = 0.f;
    float2 macc = {0.f, 0.f};

    while (true) {
        int b = e0;
        // all-but-last batches: prefetch next batch, then compute current
#pragma unroll 2
        for (; b + 4 < e1; b += 4) {
            loadB(b + 4, mtn, xwn, efn);
            __builtin_amdgcn_sched_barrier(0);   // keep prefetch ABOVE compute
            computeB(b, e1, mt, xw, ef, xdv, esum, macc);
#pragma unroll
            for (int j = 0; j < 4; j++) {
                mt[j] = mtn[j]; xw[j] = xwn[j];
                ef[j][0] = efn[j][0]; ef[j][1] = efn[j][1];
            }
        }
        // last batch: prefetch NEXT NODE's state + batch0 instead
        int nnode = node + 1;
        int ne0 = 0, ne1 = 0;
        float2 nxdv = {0.f, 0.f}, nxres = {0.f, 0.f};
        if (nnode < nhi) {
            ne0 = e1; ne1 = row_ptr[nnode + 1];
            nxdv  = xd2[(size_t)nnode * 64 + l];
            nxres = xio2[(size_t)nnode * 64 + l];
            if (ne0 < ne1) loadB(ne0, mtn, xwn, efn);
        }
        __builtin_amdgcn_sched_barrier(0);
        if (b < e1) computeB(b, e1, mt, xw, ef, xdv, esum, macc);
        epilogue(node, esum, macc, xres);
        if (nnode >= nhi) break;
        node = nnode; e0 = ne0; e1 = ne1; xdv = nxdv; xres = nxres;
        esum = 0.f; macc = make_float2(0.f, 0.f);
#pragma unroll
        for (int j = 0; j < 4; j++) {
            mt[j] = mtn[j]; xw[j] = xwn[j];
            ef[j][0] = efn[j][0]; ef[j][1] = efn[j][1];
        }
    }
}

extern "C" void kernel_launch(void* const* d_in, const int* in_sizes, int n_in,
                              void* d_out, int out_size, void* d_ws, size_t ws_size,
                              hipStream_t stream)
{
    const float* x_in   = (const float*)d_in[0];
    const int*   eidx   = (const int*)  d_in[1];
    const float* eattr  = (const float*)d_in[2];
    const float* in_g   = (const float*)d_in[3];
    const float* in_b   = (const float*)d_in[4];
    const float* proj_W = (const float*)d_in[5];
    const float* proj_b = (const float*)d_in[6];
    const float* dW1    = (const float*)d_in[7];
    const float* db1    = (const float*)d_in[8];
    const float* dW2    = (const float*)d_in[9];
    const float* db2    = (const float*)d_in[10];
    const float* cW1    = (const float*)d_in[11];
    const float* cb1    = (const float*)d_in[12];
    const float* cW2    = (const float*)d_in[13];
    const float* cb2    = (const float*)d_in[14];
    const float* rel_emb= (const float*)d_in[15];
    const float* fW1    = (const float*)d_in[16];
    const float* fb1    = (const float*)d_in[17];
    const float* fg     = (const float*)d_in[18];
    const float* fbl    = (const float*)d_in[19];
    const float* fW2    = (const float*)d_in[20];
    const float* fb2    = (const float*)d_in[21];
    const float* Wsrc   = (const float*)d_in[22];
    const float* Wdst   = (const float*)d_in[23];
    const float* Wedge  = (const float*)d_in[24];
    const float* att    = (const float*)d_in[25];
    const float* sscale = (const float*)d_in[26];
    const float* ng     = (const float*)d_in[27];
    const float* nb     = (const float*)d_in[28];

    const int* src = eidx;
    const int* dst = eidx + NE;

    char* p = (char*)d_ws;
    auto alloc = [&](size_t bytes) -> void* {
        void* r = p;
        p += (bytes + 255) & ~(size_t)255;
        return r;
    };
    uint*  xs_p    = (uint*) alloc((size_t)NN * 64 * 4);          // bf16-packed
    float* xd      = (float*)alloc((size_t)NN * HD * 4);
    uint4* efeat_h = (uint4*)alloc((size_t)(NE + 8) * 32);        // f16-packed (+pad)
    int*   counts  = (int*)  alloc((size_t)NN * 4);
    int*   row_ptr = (int*)  alloc(((size_t)NN + 1) * 4);
    int*   cursor  = (int*)  alloc((size_t)NN * 4);
    int2*  meta_c  = (int2*) alloc((size_t)(NE + 8) * 8);         // (+pad)
    int*   partials= (int*)  alloc(256);

    float* x_cur = (float*)d_out;

    const int SCAN_NBLK = (NN + 1023) / 1024;   // 49

    hipMemsetAsync(counts, 0, (size_t)NN * 4, stream);
    hipLaunchKernelGGL(count_kernel, dim3(NE / 256), dim3(256), 0, stream, dst, counts);
    hipLaunchKernelGGL(scan_a_kernel, dim3(SCAN_NBLK), dim3(1024), 0, stream,
        counts, row_ptr, partials, NN);
    hipLaunchKernelGGL(scan_b_kernel, dim3(1), dim3(64), 0, stream,
        partials, row_ptr, SCAN_NBLK, NN);
    hipLaunchKernelGGL(scan_c_kernel, dim3(SCAN_NBLK), dim3(1024), 0, stream,
        row_ptr, cursor, partials, NN);
    hipLaunchKernelGGL(edge_feat_fill_kernel, dim3(NE / 256), dim3(256), 0, stream,
        eattr, src, dst, cursor, dW1, db1, dW2, db2, cW1, cb1, cW2, cb2, rel_emb,
        fW1, fb1, fg, fbl, fW2, fb2, efeat_h, meta_c);
    hipLaunchKernelGGL(ln_proj_kernel, dim3(NN / 8), dim3(256), 0, stream,
        x_in, in_g, in_b, proj_W, proj_b, x_cur);

    const int AGG_BLOCKS = 2048;
    const int NWAVES = AGG_BLOCKS * 4;
    for (int i = 0; i < 3; i++) {
        hipLaunchKernelGGL(gemm_sd_kernel, dim3((NN + 31) / 32), dim3(512), 0, stream,
            x_cur, Wsrc + (size_t)i * HD * HD, Wdst + (size_t)i * HD * HD,
            xs_p, (float2*)xd);
        hipLaunchKernelGGL(aggregate_kernel, dim3(AGG_BLOCKS), dim3(256), 0, stream,
            xs_p, (const float2*)xd, efeat_h, meta_c, row_ptr,
            Wedge + (size_t)i * RD * HD, (const float2*)(att + (size_t)i * NH * NC),
            sscale + (size_t)i * NH,
            (const float2*)(ng + (size_t)i * HD), (const float2*)(nb + (size_t)i * HD),
            (float2*)x_cur, (i < 2) ? 1 : 0, NWAVES);
    }
}

// Round 13
// 821.293 us; speedup vs baseline: 1.0013x; 1.0013x over previous
//
#include <hip/hip_runtime.h>
#include <math.h>

#define NN 50000
#define NE 800000
#define IND 256
#define HD 128
#define NH 4
#define NC 32
#define RELN 100
#define RD 16
#define EHD 32

typedef unsigned int uint;
typedef _Float16 half2_t __attribute__((ext_vector_type(2)));

__device__ inline uint pack_bf16(float a, float b) {
    uint ua = __float_as_uint(a), ub = __float_as_uint(b);
    ua += 0x7fffu + ((ua >> 16) & 1u);
    ub += 0x7fffu + ((ub >> 16) & 1u);
    return (ua >> 16) | (ub & 0xffff0000u);
}

__device__ inline uint pack_f16(float a, float b) {
    half2_t h = { (_Float16)a, (_Float16)b };
    return __builtin_bit_cast(uint, h);
}

#if __has_builtin(__builtin_amdgcn_fdot2)
#define FDOT2(a, b, c) __builtin_amdgcn_fdot2((a), (b), (c), false)
#else
static __device__ inline float FDOT2(half2_t a, half2_t b, float c) {
    return c + (float)a.x * (float)b.x + (float)a.y * (float)b.y;
}
#endif

// 16-lane (head-group) sum via DPP row ops
__device__ inline float dpp_add(float a, const int ctrl) {
    int t;
    switch (ctrl) {
        case 0: t = __builtin_amdgcn_update_dpp(0, __float_as_int(a), 0xB1,  0xF, 0xF, true); break;
        case 1: t = __builtin_amdgcn_update_dpp(0, __float_as_int(a), 0x4E,  0xF, 0xF, true); break;
        case 2: t = __builtin_amdgcn_update_dpp(0, __float_as_int(a), 0x141, 0xF, 0xF, true); break;
        default:t = __builtin_amdgcn_update_dpp(0, __float_as_int(a), 0x140, 0xF, 0xF, true); break;
    }
    return a + __int_as_float(t);
}
__device__ inline float dpp_reduce16(float a) {
    a = dpp_add(a, 0);
    a = dpp_add(a, 1);
    a = dpp_add(a, 2);
    a = dpp_add(a, 3);
    return a;
}

// ---------------- degree count ----------------
__global__ __launch_bounds__(256) void count_kernel(
    const int* __restrict__ dst, int* __restrict__ counts)
{
    int e = blockIdx.x * 256 + threadIdx.x;
    if (e < NE) atomicAdd(&counts[dst[e]], 1);
}

// ---------------- hierarchical scan: A (per-block), B (partials), C (add) ----
__global__ __launch_bounds__(1024) void scan_a_kernel(
    const int* __restrict__ counts, int* __restrict__ row_ptr,
    int* __restrict__ partials, int n)
{
    __shared__ int wsum[16];
    int tid = threadIdx.x;
    int i = blockIdx.x * 1024 + tid;
    int v = (i < n) ? counts[i] : 0;
    int lane = tid & 63;
    int incl = v;
#pragma unroll
    for (int off = 1; off < 64; off <<= 1) {
        int t = __shfl_up(incl, off);
        if (lane >= off) incl += t;
    }
    if (lane == 63) wsum[tid >> 6] = incl;
    __syncthreads();
    if (tid < 16) {
        int w = wsum[tid];
        int inc2 = w;
#pragma unroll
        for (int off = 1; off < 16; off <<= 1) {
            int u = __shfl_up(inc2, off);
            if (tid >= off) inc2 += u;
        }
        wsum[tid] = inc2 - w;
    }
    __syncthreads();
    int excl = wsum[tid >> 6] + incl - v;
    if (i < n) row_ptr[i] = excl;
    if (tid == 1023) partials[blockIdx.x] = excl + v;
}

__global__ __launch_bounds__(64) void scan_b_kernel(
    int* __restrict__ partials, int* __restrict__ row_ptr, int nblk, int n)
{
    int tid = threadIdx.x;
    int v = (tid < nblk) ? partials[tid] : 0;
    int incl = v;
#pragma unroll
    for (int off = 1; off < 64; off <<= 1) {
        int t = __shfl_up(incl, off);
        if (tid >= off) incl += t;
    }
    if (tid < nblk) partials[tid] = incl - v;
    if (tid == nblk - 1) row_ptr[n] = incl;
}

__global__ __launch_bounds__(1024) void scan_c_kernel(
    int* __restrict__ row_ptr, int* __restrict__ cursor,
    const int* __restrict__ partials, int n)
{
    int i = blockIdx.x * 1024 + threadIdx.x;
    if (i < n) {
        int r = row_ptr[i] + partials[blockIdx.x];
        row_ptr[i] = r;
        cursor[i] = r;
    }
}

// ------- edge feature MLPs + CSR placement (fused fill), edge order -------
__global__ __launch_bounds__(256) void edge_feat_fill_kernel(
    const float* __restrict__ eattr, const int* __restrict__ src,
    const int* __restrict__ dst, int* __restrict__ cursor,
    const float* __restrict__ dW1, const float* __restrict__ db1,
    const float* __restrict__ dW2, const float* __restrict__ db2,
    const float* __restrict__ cW1, const float* __restrict__ cb1,
    const float* __restrict__ cW2, const float* __restrict__ cb2,
    const float* __restrict__ rel_emb,
    const float* __restrict__ fW1, const float* __restrict__ fb1,
    const float* __restrict__ fg,  const float* __restrict__ fbl,
    const float* __restrict__ fW2, const float* __restrict__ fb2,
    uint4* __restrict__ efeat_h, int2* __restrict__ meta_c)
{
    int e = blockIdx.x * 256 + threadIdx.x;
    // init the pad region (positions NE..NE+7) so un-clamped batch reads are safe
    if (e < 8) {
        meta_c[NE + e] = make_int2(0, 0);
        uint4 z = {0u, 0u, 0u, 0u};
        efeat_h[(size_t)(NE + e) * 2 + 0] = z;
        efeat_h[(size_t)(NE + e) * 2 + 1] = z;
    }
    if (e >= NE) return;
    float d  = eattr[(size_t)e * 3 + 0];
    float cx = eattr[(size_t)e * 3 + 1];
    int r = (int)eattr[(size_t)e * 3 + 2];
    r = min(max(r, 0), RELN - 1);
    int p = atomicAdd(&cursor[dst[e]], 1);     // CSR slot
    meta_c[p] = make_int2(src[e], __float_as_int(__log2f(d)));

    float df[RD], cf[RD];
#pragma unroll
    for (int k = 0; k < RD; k++) { df[k] = db2[k]; cf[k] = cb2[k]; }
    for (int j = 0; j < EHD; j++) {
        float h1 = fmaxf(d  * dW1[j] + db1[j], 0.f);
        float h2 = fmaxf(cx * cW1[j] + cb1[j], 0.f);
#pragma unroll
        for (int k = 0; k < RD; k++) {
            df[k] += h1 * dW2[j * RD + k];
            cf[k] += h2 * cW2[j * RD + k];
        }
    }
    float hh[2 * RD];
#pragma unroll
    for (int m = 0; m < 2 * RD; m++) hh[m] = fb1[m];
    for (int k = 0; k < RD; k++) {
        float a = df[k], b = cf[k], c = rel_emb[r * RD + k];
#pragma unroll
        for (int m = 0; m < 2 * RD; m++) {
            hh[m] += a * fW1[k * (2 * RD) + m]
                   + b * fW1[(RD + k) * (2 * RD) + m]
                   + c * fW1[(2 * RD + k) * (2 * RD) + m];
        }
    }
    float s = 0.f;
#pragma unroll
    for (int m = 0; m < 2 * RD; m++) s += hh[m];
    float mean = s * (1.f / (2 * RD));
    float s2 = 0.f;
#pragma unroll
    for (int m = 0; m < 2 * RD; m++) { float dd = hh[m] - mean; s2 += dd * dd; }
    float rs = rsqrtf(s2 * (1.f / (2 * RD)) + 1e-5f);
#pragma unroll
    for (int m = 0; m < 2 * RD; m++)
        hh[m] = fmaxf((hh[m] - mean) * rs * fg[m] + fbl[m], 0.f);

    float ef[RD];
#pragma unroll
    for (int k = 0; k < RD; k++) ef[k] = fb2[k];
    for (int m = 0; m < 2 * RD; m++) {
        float hv = hh[m];
#pragma unroll
        for (int k = 0; k < RD; k++) ef[k] += hv * fW2[m * RD + k];
    }
    uint4 e0, e1;
    e0.x = pack_f16(ef[0],  ef[1]);  e0.y = pack_f16(ef[2],  ef[3]);
    e0.z = pack_f16(ef[4],  ef[5]);  e0.w = pack_f16(ef[6],  ef[7]);
    e1.x = pack_f16(ef[8],  ef[9]);  e1.y = pack_f16(ef[10], ef[11]);
    e1.z = pack_f16(ef[12], ef[13]); e1.w = pack_f16(ef[14], ef[15]);
    efeat_h[(size_t)p * 2 + 0] = e0;
    efeat_h[(size_t)p * 2 + 1] = e1;
}

// ---------------- input LN + projection (8 nodes / block) ----------------
__global__ __launch_bounds__(256) void ln_proj_kernel(
    const float* __restrict__ x, const float* __restrict__ g, const float* __restrict__ b,
    const float* __restrict__ W, const float* __restrict__ pb, float* __restrict__ x0)
{
    __shared__ float xr[8][IND];
    __shared__ float mv[8][2];
    int nb = blockIdx.x * 8;
    int tid = threadIdx.x;
    const float4* xv = (const float4*)(x + (size_t)nb * IND);
    float4* xl = (float4*)&xr[0][0];
    xl[tid] = xv[tid];
    xl[tid + 256] = xv[tid + 256];
    __syncthreads();
    int node = tid >> 5, lane = tid & 31;
    float s1 = 0.f, s2 = 0.f;
#pragma unroll
    for (int j = 0; j < 8; j++) { float v = xr[node][lane + 32 * j]; s1 += v; s2 += v * v; }
#pragma unroll
    for (int off = 16; off >= 1; off >>= 1) { s1 += __shfl_xor(s1, off); s2 += __shfl_xor(s2, off); }
    if (lane == 0) {
        float mean = s1 * (1.f / IND);
        mv[node][0] = mean;
        mv[node][1] = rsqrtf(s2 * (1.f / IND) - mean * mean + 1e-5f);
    }
    __syncthreads();
#pragma unroll
    for (int j = 0; j < 8; j++) {
        int k = lane + 32 * j;
        xr[node][k] = (xr[node][k] - mv[node][0]) * mv[node][1] * g[k] + b[k];
    }
    __syncthreads();
    int col = tid & 127, r0 = (tid >> 7) * 4;
    float acc[4] = {0.f, 0.f, 0.f, 0.f};
    for (int k = 0; k < IND; k += 4) {
        float4 x4[4];
#pragma unroll
        for (int r = 0; r < 4; r++) x4[r] = *(const float4*)&xr[r0 + r][k];
        float w0 = W[(k + 0) * HD + col];
        float w1 = W[(k + 1) * HD + col];
        float w2 = W[(k + 2) * HD + col];
        float w3 = W[(k + 3) * HD + col];
#pragma unroll
        for (int r = 0; r < 4; r++)
            acc[r] += x4[r].x * w0 + x4[r].y * w1 + x4[r].z * w2 + x4[r].w * w3;
    }
    float pbv = pb[col];
#pragma unroll
    for (int r = 0; r < 4; r++)
        x0[(size_t)(nb + r0 + r) * HD + col] = acc[r] + pbv;
}

// ------- xs = bf16-packed x@Wsrc ; xd = f32 x@Wdst -------
__global__ __launch_bounds__(512) void gemm_sd_kernel(
    const float* __restrict__ x, const float* __restrict__ Ws, const float* __restrict__ Wd,
    uint* __restrict__ xs_p, float2* __restrict__ xd2)
{
    __shared__ float xt[32][HD];
    int nb = blockIdx.x * 32;
    int tid = threadIdx.x;
    const float4* xv = (const float4*)(x + (size_t)nb * HD);
    float4* xl = (float4*)&xt[0][0];
    int validf4 = (NN - nb >= 32) ? 1024 : (NN - nb) * 32;
#pragma unroll
    for (int u = 0; u < 2; u++) {
        int idx = tid + u * 512;
        float4 v = {0.f, 0.f, 0.f, 0.f};
        if (idx < validf4) v = xv[idx];
        xl[idx] = v;
    }
    __syncthreads();
    int half = tid >> 8;                 // 0: xs(bf16)   1: xd(f32)
    int t = tid & 255;
    int q = t & 31;                      // col quad: cols 4q..4q+3
    int r0 = (t >> 5) * 4;               // 4 rows
    const float4* W4 = (const float4*)(half ? Wd : Ws);
    float4 acc[4] = { {0,0,0,0}, {0,0,0,0}, {0,0,0,0}, {0,0,0,0} };
    for (int k = 0; k < HD; k += 4) {
        float4 xr[4];
#pragma unroll
        for (int r = 0; r < 4; r++) xr[r] = *(const float4*)&xt[r0 + r][k];
        float4 w0 = W4[(k + 0) * 32 + q];
        float4 w1 = W4[(k + 1) * 32 + q];
        float4 w2 = W4[(k + 2) * 32 + q];
        float4 w3 = W4[(k + 3) * 32 + q];
#pragma unroll
        for (int r = 0; r < 4; r++) {
            acc[r].x += xr[r].x * w0.x + xr[r].y * w1.x + xr[r].z * w2.x + xr[r].w * w3.x;
            acc[r].y += xr[r].x * w0.y + xr[r].y * w1.y + xr[r].z * w2.y + xr[r].w * w3.y;
            acc[r].z += xr[r].x * w0.z + xr[r].y * w1.z + xr[r].z * w2.z + xr[r].w * w3.z;
            acc[r].w += xr[r].x * w0.w + xr[r].y * w1.w + xr[r].z * w2.w + xr[r].w * w3.w;
        }
    }
    if (half == 0) {
#pragma unroll
        for (int r = 0; r < 4; r++) {
            int n = nb + r0 + r;
            if (n < NN) {
                uint2 pk;
                pk.x = pack_bf16(acc[r].x, acc[r].y);
                pk.y = pack_bf16(acc[r].z, acc[r].w);
                *(uint2*)&xs_p[(size_t)n * 64 + 2 * q] = pk;
            }
        }
    } else {
#pragma unroll
        for (int r = 0; r < 4; r++) {
            int n = nb + r0 + r;
            if (n < NN) {
                float2* o = &xd2[(size_t)n * 64 + 2 * q];
                o[0] = make_float2(acc[r].x, acc[r].y);
                o[1] = make_float2(acc[r].z, acc[r].w);
            }
        }
    }
}

// ------- per-layer attention aggregate + LN + ELU + residual -------
// R10 structure (best measured): wave = worker, grid-stride over nodes;
// forced pipeline via sched_barrier; DPP reduce; cross-node prefetch.
// R13: padded no-clamp loads (pad entries at NE..NE+7), tanh exp2-const fold.
__global__ __launch_bounds__(256) void aggregate_kernel(
    const uint* __restrict__ xs_p, const float2* __restrict__ xd2,
    const uint4* __restrict__ efeat_h, const int2* __restrict__ meta_c,
    const int* __restrict__ row_ptr,
    const float* __restrict__ Wedge_i, const float2* __restrict__ att2,
    const float* __restrict__ sscale_i, const float2* __restrict__ ng2,
    const float2* __restrict__ nb2, float2* __restrict__ xio2,
    int apply_dist, int nwaves)
{
    int l = threadIdx.x & 63;
    int wid = blockIdx.x * 4 + __builtin_amdgcn_readfirstlane(threadIdx.x >> 6);

    // -------- layer constants: loaded ONCE per wave --------
    int c0 = 2 * l, c1 = 2 * l + 1;
    half2_t wxh[8], wyh[8];
#pragma unroll
    for (int q = 0; q < 8; q++) {
        wxh[q] = (half2_t){ (_Float16)Wedge_i[(2 * q) * HD + c0],
                            (_Float16)Wedge_i[(2 * q + 1) * HD + c0] };
        wyh[q] = (half2_t){ (_Float16)Wedge_i[(2 * q) * HD + c1],
                            (_Float16)Wedge_i[(2 * q + 1) * HD + c1] };
    }
    float2 attv = att2[l];
    float sc = sscale_i[l >> 4];
    float2 g = ng2[l], bb = nb2[l];

    // no clamps: reads may spill into next node's edges (or the pad at NE..NE+7);
    // results are masked by (b+j < e1) in computeB
    auto loadB = [&](int b, int2* mt, uint* xw, uint4 (*ef)[2]) {
#pragma unroll
        for (int j = 0; j < 4; j++) {
            mt[j] = meta_c[b + j];
            ef[j][0] = efeat_h[(size_t)(b + j) * 2 + 0];
            ef[j][1] = efeat_h[(size_t)(b + j) * 2 + 1];
        }
#pragma unroll
        for (int j = 0; j < 4; j++) xw[j] = xs_p[(size_t)mt[j].x * 64 + l];
    };

    auto computeB = [&](int b, int e1, const int2* mt, const uint* xw,
                        const uint4 (*ef)[2], float2 xdv,
                        float& esum, float2& macc) {
#pragma unroll
        for (int j = 0; j < 4; j++) {
            const half2_t* eh = (const half2_t*)&ef[j][0];
            float efx = 0.f, efy = 0.f;
#pragma unroll
            for (int q = 0; q < 8; q++) {
                efx = FDOT2(eh[q], wxh[q], efx);
                efy = FDOT2(eh[q], wyh[q], efy);
            }
            float xvx = __uint_as_float(xw[j] << 16);
            float xvy = __uint_as_float(xw[j] & 0xffff0000u);
            float zx = xvx + xdv.x + efx;
            float zy = xvy + xdv.y + efy;
            // tanh: 1 - 2/(exp2(z*2log2e)+1)
            float px = exp2f(zx * 2.88539008f);
            float py = exp2f(zy * 2.88539008f);
            float tx = __builtin_fmaf(-2.f, __builtin_amdgcn_rcpf(px + 1.f), 1.f);
            float ty = __builtin_fmaf(-2.f, __builtin_amdgcn_rcpf(py + 1.f), 1.f);
            float a = tx * attv.x + ty * attv.y;
            a = dpp_reduce16(a);                 // 16-lane head-group sum
            // distance weight scales the LOGIT: a *= dw^sc
            if (apply_dist) a *= exp2f(__int_as_float(mt[j].y) * sc);
            float ea = exp2f(a * 1.44269504f);   // exp(a)
            ea = (b + j < e1) ? ea : 0.f;
            esum += ea;
            macc.x += xvx * ea;
            macc.y += xvy * ea;
        }
    };

    auto epilogue = [&](int node, float esum, float2 macc, float2 xres) {
        float inv = __builtin_amdgcn_rcpf(esum + 1e-8f);
        float2 outv = { macc.x * inv, macc.y * inv };
        float s1 = outv.x + outv.y;
        float s2 = outv.x * outv.x + outv.y * outv.y;
#pragma unroll
        for (int off = 32; off >= 1; off >>= 1) { s1 += __shfl_xor(s1, off); s2 += __shfl_xor(s2, off); }
        float mean = s1 * (1.f / HD);
        float var = s2 * (1.f / HD) - mean * mean;
        float rstd = rsqrtf(var + 1e-5f);
        float yx = (outv.x - mean) * rstd * g.x + bb.x;
        float yy = (outv.y - mean) * rstd * g.y + bb.y;
        float ex = (yx > 0.f) ? yx : expm1f(yx);
        float ey = (yy > 0.f) ? yy : expm1f(yy);
        float2 res;
        res.x = ex + xres.x;
        res.y = ey + xres.y;
        xio2[(size_t)node * 64 + l] = res;
    };

    int node = wid;
    if (node >= NN) return;
    int e0 = row_ptr[node], e1 = row_ptr[node + 1];
    float2 xdv  = xd2[(size_t)node * 64 + l];
    float2 xres = xio2[(size_t)node * 64 + l];
    int2 mt[4], mtn[4];
    uint xw[4], xwn[4];
    uint4 ef[4][2], efn[4][2];
    if (e0 < e1) loadB(e0, mt, xw, ef);
    float esum = 0.f;
    float2 macc = {0.f, 0.f};

    while (true) {
        int b = e0;
        // all-but-last batches: prefetch next batch, then compute current
#pragma unroll 2
        for (; b + 4 < e1; b += 4) {
            loadB(b + 4, mtn, xwn, efn);
            __builtin_amdgcn_sched_barrier(0);   // keep prefetch ABOVE compute
            computeB(b, e1, mt, xw, ef, xdv, esum, macc);
#pragma unroll
            for (int j = 0; j < 4; j++) {
                mt[j] = mtn[j]; xw[j] = xwn[j];
                ef[j][0] = efn[j][0]; ef[j][1] = efn[j][1];
            }
        }
        // last batch: prefetch NEXT NODE's state + batch0 instead
        int nnode = node + nwaves;
        int ne0 = 0, ne1 = 0;
        float2 nxdv = {0.f, 0.f}, nxres = {0.f, 0.f};
        if (nnode < NN) {
            ne0 = row_ptr[nnode]; ne1 = row_ptr[nnode + 1];
            nxdv  = xd2[(size_t)nnode * 64 + l];
            nxres = xio2[(size_t)nnode * 64 + l];
            if (ne0 < ne1) loadB(ne0, mtn, xwn, efn);
        }
        __builtin_amdgcn_sched_barrier(0);
        if (b < e1) computeB(b, e1, mt, xw, ef, xdv, esum, macc);
        epilogue(node, esum, macc, xres);
        if (nnode >= NN) break;
        node = nnode; e0 = ne0; e1 = ne1; xdv = nxdv; xres = nxres;
        esum = 0.f; macc = make_float2(0.f, 0.f);
#pragma unroll
        for (int j = 0; j < 4; j++) {
            mt[j] = mtn[j]; xw[j] = xwn[j];
            ef[j][0] = efn[j][0]; ef[j][1] = efn[j][1];
        }
    }
}

extern "C" void kernel_launch(void* const* d_in, const int* in_sizes, int n_in,
                              void* d_out, int out_size, void* d_ws, size_t ws_size,
                              hipStream_t stream)
{
    const float* x_in   = (const float*)d_in[0];
    const int*   eidx   = (const int*)  d_in[1];
    const float* eattr  = (const float*)d_in[2];
    const float* in_g   = (const float*)d_in[3];
    const float* in_b   = (const float*)d_in[4];
    const float* proj_W = (const float*)d_in[5];
    const float* proj_b = (const float*)d_in[6];
    const float* dW1    = (const float*)d_in[7];
    const float* db1    = (const float*)d_in[8];
    const float* dW2    = (const float*)d_in[9];
    const float* db2    = (const float*)d_in[10];
    const float* cW1    = (const float*)d_in[11];
    const float* cb1    = (const float*)d_in[12];
    const float* cW2    = (const float*)d_in[13];
    const float* cb2    = (const float*)d_in[14];
    const float* rel_emb= (const float*)d_in[15];
    const float* fW1    = (const float*)d_in[16];
    const float* fb1    = (const float*)d_in[17];
    const float* fg     = (const float*)d_in[18];
    const float* fbl    = (const float*)d_in[19];
    const float* fW2    = (const float*)d_in[20];
    const float* fb2    = (const float*)d_in[21];
    const float* Wsrc   = (const float*)d_in[22];
    const float* Wdst   = (const float*)d_in[23];
    const float* Wedge  = (const float*)d_in[24];
    const float* att    = (const float*)d_in[25];
    const float* sscale = (const float*)d_in[26];
    const float* ng     = (const float*)d_in[27];
    const float* nb     = (const float*)d_in[28];

    const int* src = eidx;
    const int* dst = eidx + NE;

    char* p = (char*)d_ws;
    auto alloc = [&](size_t bytes) -> void* {
        void* r = p;
        p += (bytes + 255) & ~(size_t)255;
        return r;
    };
    uint*  xs_p    = (uint*) alloc((size_t)NN * 64 * 4);          // bf16-packed
    float* xd      = (float*)alloc((size_t)NN * HD * 4);
    uint4* efeat_h = (uint4*)alloc((size_t)(NE + 8) * 32);        // f16-packed (+pad)
    int*   counts  = (int*)  alloc((size_t)NN * 4);
    int*   row_ptr = (int*)  alloc(((size_t)NN + 1) * 4);
    int*   cursor  = (int*)  alloc((size_t)NN * 4);
    int2*  meta_c  = (int2*) alloc((size_t)(NE + 8) * 8);         // (+pad)
    int*   partials= (int*)  alloc(256);

    float* x_cur = (float*)d_out;

    const int SCAN_NBLK = (NN + 1023) / 1024;   // 49

    hipMemsetAsync(counts, 0, (size_t)NN * 4, stream);
    hipLaunchKernelGGL(count_kernel, dim3(NE / 256), dim3(256), 0, stream, dst, counts);
    hipLaunchKernelGGL(scan_a_kernel, dim3(SCAN_NBLK), dim3(1024), 0, stream,
        counts, row_ptr, partials, NN);
    hipLaunchKernelGGL(scan_b_kernel, dim3(1), dim3(64), 0, stream,
        partials, row_ptr, SCAN_NBLK, NN);
    hipLaunchKernelGGL(scan_c_kernel, dim3(SCAN_NBLK), dim3(1024), 0, stream,
        row_ptr, cursor, partials, NN);
    hipLaunchKernelGGL(edge_feat_fill_kernel, dim3(NE / 256), dim3(256), 0, stream,
        eattr, src, dst, cursor, dW1, db1, dW2, db2, cW1, cb1, cW2, cb2, rel_emb,
        fW1, fb1, fg, fbl, fW2, fb2, efeat_h, meta_c);
    hipLaunchKernelGGL(ln_proj_kernel, dim3(NN / 8), dim3(256), 0, stream,
        x_in, in_g, in_b, proj_W, proj_b, x_cur);

    const int AGG_BLOCKS = 2048;
    const int NWAVES = AGG_BLOCKS * 4;
    for (int i = 0; i < 3; i++) {
        hipLaunchKernelGGL(gemm_sd_kernel, dim3((NN + 31) / 32), dim3(512), 0, stream,
            x_cur, Wsrc + (size_t)i * HD * HD, Wdst + (size_t)i * HD * HD,
            xs_p, (float2*)xd);
        hipLaunchKernelGGL(aggregate_kernel, dim3(AGG_BLOCKS), dim3(256), 0, stream,
            xs_p, (const float2*)xd, efeat_h, meta_c, row_ptr,
            Wedge + (size_t)i * RD * HD, (const float2*)(att + (size_t)i * NH * NC),
            sscale + (size_t)i * NH,
            (const float2*)(ng + (size_t)i * HD), (const float2*)(nb + (size_t)i * HD),
            (float2*)x_cur, (i < 2) ? 1 : 0, NWAVES);
    }
}

// Round 14
// 776.696 us; speedup vs baseline: 1.0588x; 1.0574x over previous
//
#include <hip/hip_runtime.h>
#include <math.h>

#define NN 50000
#define NE 800000
#define IND 256
#define HD 128
#define NH 4
#define NC 32
#define RELN 100
#define RD 16
#define EHD 32

typedef unsigned int uint;
typedef _Float16 half2_t __attribute__((ext_vector_type(2)));

__device__ inline uint pack_bf16(float a, float b) {
    uint ua = __float_as_uint(a), ub = __float_as_uint(b);
    ua += 0x7fffu + ((ua >> 16) & 1u);
    ub += 0x7fffu + ((ub >> 16) & 1u);
    return (ua >> 16) | (ub & 0xffff0000u);
}

__device__ inline uint pack_f16(float a, float b) {
    half2_t h = { (_Float16)a, (_Float16)b };
    return __builtin_bit_cast(uint, h);
}

#if __has_builtin(__builtin_amdgcn_fdot2)
#define FDOT2(a, b, c) __builtin_amdgcn_fdot2((a), (b), (c), false)
#else
static __device__ inline float FDOT2(half2_t a, half2_t b, float c) {
    return c + (float)a.x * (float)b.x + (float)a.y * (float)b.y;
}
#endif

// 16-lane (head-group) sum via DPP row ops
__device__ inline float dpp_add(float a, const int ctrl) {
    int t;
    switch (ctrl) {
        case 0: t = __builtin_amdgcn_update_dpp(0, __float_as_int(a), 0xB1,  0xF, 0xF, true); break;
        case 1: t = __builtin_amdgcn_update_dpp(0, __float_as_int(a), 0x4E,  0xF, 0xF, true); break;
        case 2: t = __builtin_amdgcn_update_dpp(0, __float_as_int(a), 0x141, 0xF, 0xF, true); break;
        default:t = __builtin_amdgcn_update_dpp(0, __float_as_int(a), 0x140, 0xF, 0xF, true); break;
    }
    return a + __int_as_float(t);
}
__device__ inline float dpp_reduce16(float a) {
    a = dpp_add(a, 0);
    a = dpp_add(a, 1);
    a = dpp_add(a, 2);
    a = dpp_add(a, 3);
    return a;
}

// ---------------- degree count ----------------
__global__ __launch_bounds__(256) void count_kernel(
    const int* __restrict__ dst, int* __restrict__ counts)
{
    int e = blockIdx.x * 256 + threadIdx.x;
    if (e < NE) atomicAdd(&counts[dst[e]], 1);
}

// ---------------- hierarchical scan: A (per-block), B (partials), C (add) ----
__global__ __launch_bounds__(1024) void scan_a_kernel(
    const int* __restrict__ counts, int* __restrict__ row_ptr,
    int* __restrict__ partials, int n)
{
    __shared__ int wsum[16];
    int tid = threadIdx.x;
    int i = blockIdx.x * 1024 + tid;
    int v = (i < n) ? counts[i] : 0;
    int lane = tid & 63;
    int incl = v;
#pragma unroll
    for (int off = 1; off < 64; off <<= 1) {
        int t = __shfl_up(incl, off);
        if (lane >= off) incl += t;
    }
    if (lane == 63) wsum[tid >> 6] = incl;
    __syncthreads();
    if (tid < 16) {
        int w = wsum[tid];
        int inc2 = w;
#pragma unroll
        for (int off = 1; off < 16; off <<= 1) {
            int u = __shfl_up(inc2, off);
            if (tid >= off) inc2 += u;
        }
        wsum[tid] = inc2 - w;
    }
    __syncthreads();
    int excl = wsum[tid >> 6] + incl - v;
    if (i < n) row_ptr[i] = excl;
    if (tid == 1023) partials[blockIdx.x] = excl + v;
}

__global__ __launch_bounds__(64) void scan_b_kernel(
    int* __restrict__ partials, int* __restrict__ row_ptr, int nblk, int n)
{
    int tid = threadIdx.x;
    int v = (tid < nblk) ? partials[tid] : 0;
    int incl = v;
#pragma unroll
    for (int off = 1; off < 64; off <<= 1) {
        int t = __shfl_up(incl, off);
        if (tid >= off) incl += t;
    }
    if (tid < nblk) partials[tid] = incl - v;
    if (tid == nblk - 1) row_ptr[n] = incl;
}

__global__ __launch_bounds__(1024) void scan_c_kernel(
    int* __restrict__ row_ptr, int* __restrict__ cursor,
    const int* __restrict__ partials, int n)
{
    int i = blockIdx.x * 1024 + threadIdx.x;
    if (i < n) {
        int r = row_ptr[i] + partials[blockIdx.x];
        row_ptr[i] = r;
        cursor[i] = r;
    }
}

// ------- edge feature MLPs + CSR placement (fused fill), edge order -------
__global__ __launch_bounds__(256) void edge_feat_fill_kernel(
    const float* __restrict__ eattr, const int* __restrict__ src,
    const int* __restrict__ dst, int* __restrict__ cursor,
    const float* __restrict__ dW1, const float* __restrict__ db1,
    const float* __restrict__ dW2, const float* __restrict__ db2,
    const float* __restrict__ cW1, const float* __restrict__ cb1,
    const float* __restrict__ cW2, const float* __restrict__ cb2,
    const float* __restrict__ rel_emb,
    const float* __restrict__ fW1, const float* __restrict__ fb1,
    const float* __restrict__ fg,  const float* __restrict__ fbl,
    const float* __restrict__ fW2, const float* __restrict__ fb2,
    uint4* __restrict__ efeat_h, int2* __restrict__ meta_c)
{
    int e = blockIdx.x * 256 + threadIdx.x;
    if (e >= NE) return;
    float d  = eattr[(size_t)e * 3 + 0];
    float cx = eattr[(size_t)e * 3 + 1];
    int r = (int)eattr[(size_t)e * 3 + 2];
    r = min(max(r, 0), RELN - 1);
    int p = atomicAdd(&cursor[dst[e]], 1);     // CSR slot
    meta_c[p] = make_int2(src[e], __float_as_int(__log2f(d)));

    float df[RD], cf[RD];
#pragma unroll
    for (int k = 0; k < RD; k++) { df[k] = db2[k]; cf[k] = cb2[k]; }
    for (int j = 0; j < EHD; j++) {
        float h1 = fmaxf(d  * dW1[j] + db1[j], 0.f);
        float h2 = fmaxf(cx * cW1[j] + cb1[j], 0.f);
#pragma unroll
        for (int k = 0; k < RD; k++) {
            df[k] += h1 * dW2[j * RD + k];
            cf[k] += h2 * cW2[j * RD + k];
        }
    }
    float hh[2 * RD];
#pragma unroll
    for (int m = 0; m < 2 * RD; m++) hh[m] = fb1[m];
    for (int k = 0; k < RD; k++) {
        float a = df[k], b = cf[k], c = rel_emb[r * RD + k];
#pragma unroll
        for (int m = 0; m < 2 * RD; m++) {
            hh[m] += a * fW1[k * (2 * RD) + m]
                   + b * fW1[(RD + k) * (2 * RD) + m]
                   + c * fW1[(2 * RD + k) * (2 * RD) + m];
        }
    }
    float s = 0.f;
#pragma unroll
    for (int m = 0; m < 2 * RD; m++) s += hh[m];
    float mean = s * (1.f / (2 * RD));
    float s2 = 0.f;
#pragma unroll
    for (int m = 0; m < 2 * RD; m++) { float dd = hh[m] - mean; s2 += dd * dd; }
    float rs = rsqrtf(s2 * (1.f / (2 * RD)) + 1e-5f);
#pragma unroll
    for (int m = 0; m < 2 * RD; m++)
        hh[m] = fmaxf((hh[m] - mean) * rs * fg[m] + fbl[m], 0.f);

    float ef[RD];
#pragma unroll
    for (int k = 0; k < RD; k++) ef[k] = fb2[k];
    for (int m = 0; m < 2 * RD; m++) {
        float hv = hh[m];
#pragma unroll
        for (int k = 0; k < RD; k++) ef[k] += hv * fW2[m * RD + k];
    }
    uint4 e0, e1;
    e0.x = pack_f16(ef[0],  ef[1]);  e0.y = pack_f16(ef[2],  ef[3]);
    e0.z = pack_f16(ef[4],  ef[5]);  e0.w = pack_f16(ef[6],  ef[7]);
    e1.x = pack_f16(ef[8],  ef[9]);  e1.y = pack_f16(ef[10], ef[11]);
    e1.z = pack_f16(ef[12], ef[13]); e1.w = pack_f16(ef[14], ef[15]);
    efeat_h[(size_t)p * 2 + 0] = e0;
    efeat_h[(size_t)p * 2 + 1] = e1;
}

// ---------------- input LN + projection (8 nodes / block) ----------------
__global__ __launch_bounds__(256) void ln_proj_kernel(
    const float* __restrict__ x, const float* __restrict__ g, const float* __restrict__ b,
    const float* __restrict__ W, const float* __restrict__ pb, float* __restrict__ x0)
{
    __shared__ float xr[8][IND];
    __shared__ float mv[8][2];
    int nb = blockIdx.x * 8;
    int tid = threadIdx.x;
    const float4* xv = (const float4*)(x + (size_t)nb * IND);
    float4* xl = (float4*)&xr[0][0];
    xl[tid] = xv[tid];
    xl[tid + 256] = xv[tid + 256];
    __syncthreads();
    int node = tid >> 5, lane = tid & 31;
    float s1 = 0.f, s2 = 0.f;
#pragma unroll
    for (int j = 0; j < 8; j++) { float v = xr[node][lane + 32 * j]; s1 += v; s2 += v * v; }
#pragma unroll
    for (int off = 16; off >= 1; off >>= 1) { s1 += __shfl_xor(s1, off); s2 += __shfl_xor(s2, off); }
    if (lane == 0) {
        float mean = s1 * (1.f / IND);
        mv[node][0] = mean;
        mv[node][1] = rsqrtf(s2 * (1.f / IND) - mean * mean + 1e-5f);
    }
    __syncthreads();
#pragma unroll
    for (int j = 0; j < 8; j++) {
        int k = lane + 32 * j;
        xr[node][k] = (xr[node][k] - mv[node][0]) * mv[node][1] * g[k] + b[k];
    }
    __syncthreads();
    int col = tid & 127, r0 = (tid >> 7) * 4;
    float acc[4] = {0.f, 0.f, 0.f, 0.f};
    for (int k = 0; k < IND; k += 4) {
        float4 x4[4];
#pragma unroll
        for (int r = 0; r < 4; r++) x4[r] = *(const float4*)&xr[r0 + r][k];
        float w0 = W[(k + 0) * HD + col];
        float w1 = W[(k + 1) * HD + col];
        float w2 = W[(k + 2) * HD + col];
        float w3 = W[(k + 3) * HD + col];
#pragma unroll
        for (int r = 0; r < 4; r++)
            acc[r] += x4[r].x * w0 + x4[r].y * w1 + x4[r].z * w2 + x4[r].w * w3;
    }
    float pbv = pb[col];
#pragma unroll
    for (int r = 0; r < 4; r++)
        x0[(size_t)(nb + r0 + r) * HD + col] = acc[r] + pbv;
}

// ------- xs = bf16-packed x@Wsrc ; xd = f32 x@Wdst -------
__global__ __launch_bounds__(512) void gemm_sd_kernel(
    const float* __restrict__ x, const float* __restrict__ Ws, const float* __restrict__ Wd,
    uint* __restrict__ xs_p, float2* __restrict__ xd2)
{
    __shared__ float xt[32][HD];
    int nb = blockIdx.x * 32;
    int tid = threadIdx.x;
    const float4* xv = (const float4*)(x + (size_t)nb * HD);
    float4* xl = (float4*)&xt[0][0];
    int validf4 = (NN - nb >= 32) ? 1024 : (NN - nb) * 32;
#pragma unroll
    for (int u = 0; u < 2; u++) {
        int idx = tid + u * 512;
        float4 v = {0.f, 0.f, 0.f, 0.f};
        if (idx < validf4) v = xv[idx];
        xl[idx] = v;
    }
    __syncthreads();
    int half = tid >> 8;                 // 0: xs(bf16)   1: xd(f32)
    int t = tid & 255;
    int q = t & 31;                      // col quad: cols 4q..4q+3
    int r0 = (t >> 5) * 4;               // 4 rows
    const float4* W4 = (const float4*)(half ? Wd : Ws);
    float4 acc[4] = { {0,0,0,0}, {0,0,0,0}, {0,0,0,0}, {0,0,0,0} };
    for (int k = 0; k < HD; k += 4) {
        float4 xr[4];
#pragma unroll
        for (int r = 0; r < 4; r++) xr[r] = *(const float4*)&xt[r0 + r][k];
        float4 w0 = W4[(k + 0) * 32 + q];
        float4 w1 = W4[(k + 1) * 32 + q];
        float4 w2 = W4[(k + 2) * 32 + q];
        float4 w3 = W4[(k + 3) * 32 + q];
#pragma unroll
        for (int r = 0; r < 4; r++) {
            acc[r].x += xr[r].x * w0.x + xr[r].y * w1.x + xr[r].z * w2.x + xr[r].w * w3.x;
            acc[r].y += xr[r].x * w0.y + xr[r].y * w1.y + xr[r].z * w2.y + xr[r].w * w3.y;
            acc[r].z += xr[r].x * w0.z + xr[r].y * w1.z + xr[r].z * w2.z + xr[r].w * w3.z;
            acc[r].w += xr[r].x * w0.w + xr[r].y * w1.w + xr[r].z * w2.w + xr[r].w * w3.w;
        }
    }
    if (half == 0) {
#pragma unroll
        for (int r = 0; r < 4; r++) {
            int n = nb + r0 + r;
            if (n < NN) {
                uint2 pk;
                pk.x = pack_bf16(acc[r].x, acc[r].y);
                pk.y = pack_bf16(acc[r].z, acc[r].w);
                *(uint2*)&xs_p[(size_t)n * 64 + 2 * q] = pk;
            }
        }
    } else {
#pragma unroll
        for (int r = 0; r < 4; r++) {
            int n = nb + r0 + r;
            if (n < NN) {
                float2* o = &xd2[(size_t)n * 64 + 2 * q];
                o[0] = make_float2(acc[r].x, acc[r].y);
                o[1] = make_float2(acc[r].z, acc[r].w);
            }
        }
    }
}

// ------- per-layer attention aggregate + LN + ELU + residual -------
// EXACT R10 structure (best measured: 134 us/dispatch): wave = worker,
// grid-stride over nodes; forced pipeline via sched_barrier; DPP reduce;
// cross-node prefetch; CLAMPED loads; native __expf.
__global__ __launch_bounds__(256) void aggregate_kernel(
    const uint* __restrict__ xs_p, const float2* __restrict__ xd2,
    const uint4* __restrict__ efeat_h, const int2* __restrict__ meta_c,
    const int* __restrict__ row_ptr,
    const float* __restrict__ Wedge_i, const float2* __restrict__ att2,
    const float* __restrict__ sscale_i, const float2* __restrict__ ng2,
    const float2* __restrict__ nb2, float2* __restrict__ xio2,
    int apply_dist, int nwaves)
{
    int l = threadIdx.x & 63;
    int wid = blockIdx.x * 4 + __builtin_amdgcn_readfirstlane(threadIdx.x >> 6);

    // -------- layer constants: loaded ONCE per wave --------
    int c0 = 2 * l, c1 = 2 * l + 1;
    half2_t wxh[8], wyh[8];
#pragma unroll
    for (int q = 0; q < 8; q++) {
        wxh[q] = (half2_t){ (_Float16)Wedge_i[(2 * q) * HD + c0],
                            (_Float16)Wedge_i[(2 * q + 1) * HD + c0] };
        wyh[q] = (half2_t){ (_Float16)Wedge_i[(2 * q) * HD + c1],
                            (_Float16)Wedge_i[(2 * q + 1) * HD + c1] };
    }
    float2 attv = att2[l];
    float sc = sscale_i[l >> 4];
    float2 g = ng2[l], bb = nb2[l];

    auto loadB = [&](int b, int e1, int2* mt, uint* xw, uint4 (*ef)[2]) {
#pragma unroll
        for (int j = 0; j < 4; j++) {
            int pp = min(b + j, e1 - 1);
            mt[j] = meta_c[pp];
            ef[j][0] = efeat_h[(size_t)pp * 2 + 0];
            ef[j][1] = efeat_h[(size_t)pp * 2 + 1];
        }
#pragma unroll
        for (int j = 0; j < 4; j++) xw[j] = xs_p[(size_t)mt[j].x * 64 + l];
    };

    auto computeB = [&](int b, int e1, const int2* mt, const uint* xw,
                        const uint4 (*ef)[2], float2 xdv,
                        float& esum, float2& macc) {
#pragma unroll
        for (int j = 0; j < 4; j++) {
            const half2_t* eh = (const half2_t*)&ef[j][0];
            float efx = 0.f, efy = 0.f;
#pragma unroll
            for (int q = 0; q < 8; q++) {
                efx = FDOT2(eh[q], wxh[q], efx);
                efy = FDOT2(eh[q], wyh[q], efy);
            }
            float xvx = __uint_as_float(xw[j] << 16);
            float xvy = __uint_as_float(xw[j] & 0xffff0000u);
            float zx = xvx + xdv.x + efx;
            float zy = xvy + xdv.y + efy;
            float tx = 1.f - 2.f * __builtin_amdgcn_rcpf(__expf(2.f * zx) + 1.f);
            float ty = 1.f - 2.f * __builtin_amdgcn_rcpf(__expf(2.f * zy) + 1.f);
            float a = tx * attv.x + ty * attv.y;
            a = dpp_reduce16(a);                 // 16-lane head-group sum
            // distance weight scales the LOGIT: a *= dw^sc (native v_exp)
            if (apply_dist) a *= __builtin_amdgcn_exp2f(__int_as_float(mt[j].y) * sc);
            float ea = __expf(a);
            ea = (b + j < e1) ? ea : 0.f;
            esum += ea;
            macc.x += xvx * ea;
            macc.y += xvy * ea;
        }
    };

    auto epilogue = [&](int node, float esum, float2 macc, float2 xres) {
        float inv = __builtin_amdgcn_rcpf(esum + 1e-8f);
        float2 outv = { macc.x * inv, macc.y * inv };
        float s1 = outv.x + outv.y;
        float s2 = outv.x * outv.x + outv.y * outv.y;
#pragma unroll
        for (int off = 32; off >= 1; off >>= 1) { s1 += __shfl_xor(s1, off); s2 += __shfl_xor(s2, off); }
        float mean = s1 * (1.f / HD);
        float var = s2 * (1.f / HD) - mean * mean;
        float rstd = rsqrtf(var + 1e-5f);
        float yx = (outv.x - mean) * rstd * g.x + bb.x;
        float yy = (outv.y - mean) * rstd * g.y + bb.y;
        float ex = (yx > 0.f) ? yx : expm1f(yx);
        float ey = (yy > 0.f) ? yy : expm1f(yy);
        float2 res;
        res.x = ex + xres.x;
        res.y = ey + xres.y;
        xio2[(size_t)node * 64 + l] = res;
    };

    int node = wid;
    if (node >= NN) return;
    int e0 = row_ptr[node], e1 = row_ptr[node + 1];
    float2 xdv  = xd2[(size_t)node * 64 + l];
    float2 xres = xio2[(size_t)node * 64 + l];
    int2 mt[4], mtn[4];
    uint xw[4], xwn[4];
    uint4 ef[4][2], efn[4][2];
    if (e0 < e1) loadB(e0, e1, mt, xw, ef);
    float esum = 0.f;
    float2 macc = {0.f, 0.f};

    while (true) {
        int b = e0;
        // all-but-last batches: prefetch next batch, then compute current
#pragma unroll 2
        for (; b + 4 < e1; b += 4) {
            loadB(b + 4, e1, mtn, xwn, efn);
            __builtin_amdgcn_sched_barrier(0);   // keep prefetch ABOVE compute
            computeB(b, e1, mt, xw, ef, xdv, esum, macc);
#pragma unroll
            for (int j = 0; j < 4; j++) {
                mt[j] = mtn[j]; xw[j] = xwn[j];
                ef[j][0] = efn[j][0]; ef[j][1] = efn[j][1];
            }
        }
        // last batch: prefetch NEXT NODE's state + batch0 instead
        int nnode = node + nwaves;
        int ne0 = 0, ne1 = 0;
        float2 nxdv = {0.f, 0.f}, nxres = {0.f, 0.f};
        if (nnode < NN) {
            ne0 = row_ptr[nnode]; ne1 = row_ptr[nnode + 1];
            nxdv  = xd2[(size_t)nnode * 64 + l];
            nxres = xio2[(size_t)nnode * 64 + l];
            if (ne0 < ne1) loadB(ne0, ne1, mtn, xwn, efn);
        }
        __builtin_amdgcn_sched_barrier(0);
        if (b < e1) computeB(b, e1, mt, xw, ef, xdv, esum, macc);
        epilogue(node, esum, macc, xres);
        if (nnode >= NN) break;
        node = nnode; e0 = ne0; e1 = ne1; xdv = nxdv; xres = nxres;
        esum = 0.f; macc = make_float2(0.f, 0.f);
#pragma unroll
        for (int j = 0; j < 4; j++) {
            mt[j] = mtn[j]; xw[j] = xwn[j];
            ef[j][0] = efn[j][0]; ef[j][1] = efn[j][1];
        }
    }
}

extern "C" void kernel_launch(void* const* d_in, const int* in_sizes, int n_in,
                              void* d_out, int out_size, void* d_ws, size_t ws_size,
                              hipStream_t stream)
{
    const float* x_in   = (const float*)d_in[0];
    const int*   eidx   = (const int*)  d_in[1];
    const float* eattr  = (const float*)d_in[2];
    const float* in_g   = (const float*)d_in[3];
    const float* in_b   = (const float*)d_in[4];
    const float* proj_W = (const float*)d_in[5];
    const float* proj_b = (const float*)d_in[6];
    const float* dW1    = (const float*)d_in[7];
    const float* db1    = (const float*)d_in[8];
    const float* dW2    = (const float*)d_in[9];
    const float* db2    = (const float*)d_in[10];
    const float* cW1    = (const float*)d_in[11];
    const float* cb1    = (const float*)d_in[12];
    const float* cW2    = (const float*)d_in[13];
    const float* cb2    = (const float*)d_in[14];
    const float* rel_emb= (const float*)d_in[15];
    const float* fW1    = (const float*)d_in[16];
    const float* fb1    = (const float*)d_in[17];
    const float* fg     = (const float*)d_in[18];
    const float* fbl    = (const float*)d_in[19];
    const float* fW2    = (const float*)d_in[20];
    const float* fb2    = (const float*)d_in[21];
    const float* Wsrc   = (const float*)d_in[22];
    const float* Wdst   = (const float*)d_in[23];
    const float* Wedge  = (const float*)d_in[24];
    const float* att    = (const float*)d_in[25];
    const float* sscale = (const float*)d_in[26];
    const float* ng     = (const float*)d_in[27];
    const float* nb     = (const float*)d_in[28];

    const int* src = eidx;
    const int* dst = eidx + NE;

    char* p = (char*)d_ws;
    auto alloc = [&](size_t bytes) -> void* {
        void* r = p;
        p += (bytes + 255) & ~(size_t)255;
        return r;
    };
    uint*  xs_p    = (uint*) alloc((size_t)NN * 64 * 4);          // bf16-packed
    float* xd      = (float*)alloc((size_t)NN * HD * 4);
    uint4* efeat_h = (uint4*)alloc((size_t)(NE + 8) * 32);        // f16-packed
    int*   counts  = (int*)  alloc((size_t)NN * 4);
    int*   row_ptr = (int*)  alloc(((size_t)NN + 1) * 4);
    int*   cursor  = (int*)  alloc((size_t)NN * 4);
    int2*  meta_c  = (int2*) alloc((size_t)(NE + 8) * 8);
    int*   partials= (int*)  alloc(256);

    float* x_cur = (float*)d_out;

    const int SCAN_NBLK = (NN + 1023) / 1024;   // 49

    hipMemsetAsync(counts, 0, (size_t)NN * 4, stream);
    hipLaunchKernelGGL(count_kernel, dim3(NE / 256), dim3(256), 0, stream, dst, counts);
    hipLaunchKernelGGL(scan_a_kernel, dim3(SCAN_NBLK), dim3(1024), 0, stream,
        counts, row_ptr, partials, NN);
    hipLaunchKernelGGL(scan_b_kernel, dim3(1), dim3(64), 0, stream,
        partials, row_ptr, SCAN_NBLK, NN);
    hipLaunchKernelGGL(scan_c_kernel, dim3(SCAN_NBLK), dim3(1024), 0, stream,
        row_ptr, cursor, partials, NN);
    hipLaunchKernelGGL(edge_feat_fill_kernel, dim3(NE / 256), dim3(256), 0, stream,
        eattr, src, dst, cursor, dW1, db1, dW2, db2, cW1, cb1, cW2, cb2, rel_emb,
        fW1, fb1, fg, fbl, fW2, fb2, efeat_h, meta_c);
    hipLaunchKernelGGL(ln_proj_kernel, dim3(NN / 8), dim3(256), 0, stream,
        x_in, in_g, in_b, proj_W, proj_b, x_cur);

    const int AGG_BLOCKS = 2048;
    const int NWAVES = AGG_BLOCKS * 4;
    for (int i = 0; i < 3; i++) {
        hipLaunchKernelGGL(gemm_sd_kernel, dim3((NN + 31) / 32), dim3(512), 0, stream,
            x_cur, Wsrc + (size_t)i * HD * HD, Wdst + (size_t)i * HD * HD,
            xs_p, (float2*)xd);
        hipLaunchKernelGGL(aggregate_kernel, dim3(AGG_BLOCKS), dim3(256), 0, stream,
            xs_p, (const float2*)xd, efeat_h, meta_c, row_ptr,
            Wedge + (size_t)i * RD * HD, (const float2*)(att + (size_t)i * NH * NC),
            sscale + (size_t)i * NH,
            (const float2*)(ng + (size_t)i * HD), (const float2*)(nb + (size_t)i * HD),
            (float2*)x_cur, (i < 2) ? 1 : 0, NWAVES);
    }
}